// Round 3
// baseline (141.226 us; speedup 1.0000x reference)
//
#include <hip/hip_runtime.h>
#include <hip/hip_fp16.h>

#define N_DET 128
#define N_T   2048
#define NPIX  65536   // 256*256
#define NBATCH 4

// 16B vector with 8-byte alignment guarantee (HW needs only dword alignment
// for global_load_dwordx4; records are 8B so t/t+1 pair is 8B-aligned).
typedef float f4_t __attribute__((ext_vector_type(4)));
typedef f4_t __attribute__((aligned(8))) f4a8_t;

// Kernel 1: transpose+pack sino (B, N_DET, N_T) fp32 -> ws (N_DET, N_T) of
// 8-byte records: { s_t[b0..b3] } as 4 fp16. Total ws = 2 MB -> fits in a
// per-XCD L2 (4 MB) WITH headroom so the lut stream doesn't thrash it.
__global__ __launch_bounds__(256) void sino_pack_kernel(
    const float* __restrict__ sino, float2* __restrict__ ws) {
  const int idx = blockIdx.x * blockDim.x + threadIdx.x;  // idx = d*N_T + t
  const __half2 lo = __floats2half2_rn(
      __builtin_nontemporal_load(sino + 0 * N_DET * N_T + idx),
      __builtin_nontemporal_load(sino + 1 * N_DET * N_T + idx));
  const __half2 hi = __floats2half2_rn(
      __builtin_nontemporal_load(sino + 2 * N_DET * N_T + idx),
      __builtin_nontemporal_load(sino + 3 * N_DET * N_T + idx));
  union { struct { __half2 a, b; } h; float2 f; } u;
  u.h.a = lo;
  u.h.b = hi;
  ws[idx] = u.f;  // normal store: we WANT these lines resident in L2
}

// Kernel 2: one wave per pixel; lane l handles detectors 2l, 2l+1.
// lut read: non-temporal (streamed once, must not evict the sino hot set).
// Gather: one 16B dwordx4 (8B-aligned) = records t and t+1, all 4 batches.
__global__ __launch_bounds__(256) void das_packed_kernel(
    const float* __restrict__ lut, const unsigned char* __restrict__ S8,
    float* __restrict__ out) {
  const int lane = threadIdx.x & 63;
  const int p = blockIdx.x * 4 + (threadIdx.x >> 6);  // pixel id, 4 waves/block

  const f4_t lv = __builtin_nontemporal_load(
      reinterpret_cast<const f4_t*>(lut + (size_t)p * 2 * N_DET) + lane);

  float acc0 = 0.f, acc1 = 0.f, acc2 = 0.f, acc3 = 0.f;
  float wsum = 0.f;

#pragma unroll
  for (int j = 0; j < 2; ++j) {
    const int d = 2 * lane + j;
    const float tof = j ? lv.z : lv.x;
    const float a   = j ? lv.w : lv.y;

    const float kf = floorf(tof);
    const bool valid = (kf >= 0.0f) && (kf < (float)(N_T - 1));
    const float kcl = fminf(fmaxf(kf, 0.0f), (float)(N_T - 2));
    const int k0 = (int)kcl;

    const float apd =
        0.5f - 0.5f * cosf(6.28318530717958647692f *
                           (1.0f / (float)(N_DET - 1)) * (float)d);
    wsum += apd;
    const float w = valid ? apd : 0.0f;
    const float om = 1.0f - a;

    // 16B = record k0 (8B: 4 batches fp16) + record k0+1.
    const f4a8_t v = *reinterpret_cast<const f4a8_t*>(
        S8 + ((size_t)d * N_T + k0) * 8);
    const __half2* hp = reinterpret_cast<const __half2*>(&v);
    const float2 s0a = __half22float2(hp[0]);  // t:   b0,b1
    const float2 s0b = __half22float2(hp[1]);  // t:   b2,b3
    const float2 s1a = __half22float2(hp[2]);  // t+1: b0,b1
    const float2 s1b = __half22float2(hp[3]);  // t+1: b2,b3

    acc0 += w * (om * s0a.x + a * s1a.x);
    acc1 += w * (om * s0a.y + a * s1a.y);
    acc2 += w * (om * s0b.x + a * s1b.x);
    acc3 += w * (om * s0b.y + a * s1b.y);
  }

#pragma unroll
  for (int off = 32; off > 0; off >>= 1) {
    acc0 += __shfl_xor(acc0, off);
    acc1 += __shfl_xor(acc1, off);
    acc2 += __shfl_xor(acc2, off);
    acc3 += __shfl_xor(acc3, off);
    wsum += __shfl_xor(wsum, off);
  }

  if (lane == 0) {
    const float inv = 1.0f / fmaxf(wsum, 1.17549435e-38f);
    __builtin_nontemporal_store(acc0 * inv, out + 0 * NPIX + p);
    __builtin_nontemporal_store(acc1 * inv, out + 1 * NPIX + p);
    __builtin_nontemporal_store(acc2 * inv, out + 2 * NPIX + p);
    __builtin_nontemporal_store(acc3 * inv, out + 3 * NPIX + p);
  }
}

// Fallback (no workspace): direct fp32 gather from original layout.
__global__ __launch_bounds__(256) void das_fallback_kernel(
    const float* __restrict__ lut, const float* __restrict__ S,
    float* __restrict__ out) {
  const int lane = threadIdx.x & 63;
  const int p = blockIdx.x * 4 + (threadIdx.x >> 6);

  const float4 lv =
      reinterpret_cast<const float4*>(lut + (size_t)p * 2 * N_DET)[lane];

  float acc0 = 0.f, acc1 = 0.f, acc2 = 0.f, acc3 = 0.f;
  float wsum = 0.f;

#pragma unroll
  for (int j = 0; j < 2; ++j) {
    const int d = 2 * lane + j;
    const float tof = j ? lv.z : lv.x;
    const float a   = j ? lv.w : lv.y;
    const float kf = floorf(tof);
    const bool valid = (kf >= 0.0f) && (kf < (float)(N_T - 1));
    const float kcl = fminf(fmaxf(kf, 0.0f), (float)(N_T - 2));
    const int k0 = (int)kcl;
    const float apd =
        0.5f - 0.5f * cosf(6.28318530717958647692f *
                           (1.0f / (float)(N_DET - 1)) * (float)d);
    wsum += apd;
    const float w = valid ? apd : 0.0f;
    const float om = 1.0f - a;
    const float* row = S + (size_t)d * N_T + k0;
    acc0 += w * (om * row[0 * N_DET * N_T] + a * row[0 * N_DET * N_T + 1]);
    acc1 += w * (om * row[1 * N_DET * N_T] + a * row[1 * N_DET * N_T + 1]);
    acc2 += w * (om * row[2 * N_DET * N_T] + a * row[2 * N_DET * N_T + 1]);
    acc3 += w * (om * row[3 * N_DET * N_T] + a * row[3 * N_DET * N_T + 1]);
  }

#pragma unroll
  for (int off = 32; off > 0; off >>= 1) {
    acc0 += __shfl_xor(acc0, off);
    acc1 += __shfl_xor(acc1, off);
    acc2 += __shfl_xor(acc2, off);
    acc3 += __shfl_xor(acc3, off);
    wsum += __shfl_xor(wsum, off);
  }

  if (lane == 0) {
    const float inv = 1.0f / fmaxf(wsum, 1.17549435e-38f);
    out[0 * NPIX + p] = acc0 * inv;
    out[1 * NPIX + p] = acc1 * inv;
    out[2 * NPIX + p] = acc2 * inv;
    out[3 * NPIX + p] = acc3 * inv;
  }
}

extern "C" void kernel_launch(void* const* d_in, const int* in_sizes, int n_in,
                              void* d_out, int out_size, void* d_ws, size_t ws_size,
                              hipStream_t stream) {
  const float* sino = (const float*)d_in[0];  // (B,1,N_DET,N_T) fp32
  const float* lut  = (const float*)d_in[1];  // (NY,NX,N_DET,2) fp32
  float* out = (float*)d_out;                 // (B,1,NY,NX) fp32

  const size_t need = (size_t)N_DET * N_T * 8;  // 2 MB packed ws
  if (ws_size >= need) {
    float2* ws = (float2*)d_ws;
    sino_pack_kernel<<<(N_DET * N_T) / 256, 256, 0, stream>>>(sino, ws);
    das_packed_kernel<<<NPIX / 4, 256, 0, stream>>>(
        lut, (const unsigned char*)d_ws, out);
  } else {
    das_fallback_kernel<<<NPIX / 4, 256, 0, stream>>>(lut, sino, out);
  }
}

// Round 4
// 133.943 us; speedup vs baseline: 1.0544x; 1.0544x over previous
//
#include <hip/hip_runtime.h>
#include <hip/hip_fp16.h>

#define N_DET 128
#define N_T   2048
#define NPIX  65536   // 256*256
#define NBATCH 4
#define PIX_PER_BLK 64
#define NGRP 4
#define DETS_PER_GRP 32   // NGRP * DETS_PER_GRP == N_DET

typedef float f4_t __attribute__((ext_vector_type(4)));
typedef f4_t __attribute__((aligned(8))) f4a8_t;

// Kernel 1: transpose+pack sino (B, N_DET, N_T) fp32 -> ws (N_DET, N_T) of
// 8-byte records { s_t[b0..b3] } as 4 fp16. ws = 2 MB -> L2-resident.
__global__ __launch_bounds__(256) void sino_pack_kernel(
    const float* __restrict__ sino, float2* __restrict__ ws) {
  const int idx = blockIdx.x * blockDim.x + threadIdx.x;  // idx = d*N_T + t
  const __half2 lo = __floats2half2_rn(
      __builtin_nontemporal_load(sino + 0 * N_DET * N_T + idx),
      __builtin_nontemporal_load(sino + 1 * N_DET * N_T + idx));
  const __half2 hi = __floats2half2_rn(
      __builtin_nontemporal_load(sino + 2 * N_DET * N_T + idx),
      __builtin_nontemporal_load(sino + 3 * N_DET * N_T + idx));
  union { struct { __half2 a, b; } h; float2 f; } u;
  u.h.a = lo;
  u.h.b = hi;
  ws[idx] = u.f;
}

// Kernel 2: ILP-oriented. Block = 256 threads as (64 pixels) x (4 det groups).
// Thread (x,y): pixel p=blk*64+x, dets y*32 .. y*32+31, private fp32 acc[4].
// No wave shuffles; one LDS reduce at the end. Norm = 63.5 exactly
// (sum_{d=0..127} 0.5-0.5cos(2pi d/127) = 64 - 0.5*cos(2pi) = 63.5).
__global__ __launch_bounds__(256) void das_kernel(
    const float* __restrict__ lut, const unsigned char* __restrict__ S8,
    float* __restrict__ out) {
  __shared__ float apod_s[N_DET];
  __shared__ float red[NGRP][PIX_PER_BLK][NBATCH];

  const int x = threadIdx.x;         // 0..63  (pixel lane)
  const int y = threadIdx.y;         // 0..3   (det group)
  const int tid = y * PIX_PER_BLK + x;
  const int p = blockIdx.x * PIX_PER_BLK + x;

  if (tid < N_DET) {
    apod_s[tid] = 0.5f - 0.5f * cosf(6.28318530717958647692f *
                                     ((float)tid / (float)(N_DET - 1)));
  }
  __syncthreads();

  // This thread's lut run: 32 consecutive dets of pixel p = 256 B contiguous,
  // 16B-aligned (offset is a multiple of 256 floats).
  const float* lutp = lut + ((size_t)p * N_DET + y * DETS_PER_GRP) * 2;
  const int dbase0 = y * DETS_PER_GRP;

  float a0 = 0.f, a1 = 0.f, a2 = 0.f, a3 = 0.f;

#pragma unroll 2
  for (int c = 0; c < DETS_PER_GRP / 4; ++c) {  // chunks of 4 detectors
    const f4_t l0 = *reinterpret_cast<const f4_t*>(lutp + c * 8);      // d+0,d+1
    const f4_t l1 = *reinterpret_cast<const f4_t*>(lutp + c * 8 + 4);  // d+2,d+3
    const float tofs[4] = {l0.x, l0.z, l1.x, l1.z};
    const float als[4]  = {l0.y, l0.w, l1.y, l1.w};
    const int dbase = dbase0 + c * 4;

    // Issue all 4 gathers first (independent, pipelined by the compiler).
    f4_t v[4];
    float kfs[4];
#pragma unroll
    for (int j = 0; j < 4; ++j) {
      const float kf = floorf(tofs[j]);
      kfs[j] = kf;
      const float kcl = fminf(fmaxf(kf, 0.0f), (float)(N_T - 2));
      const unsigned k0 = (unsigned)(int)kcl;
      const unsigned voff = ((unsigned)(dbase + j) * N_T + k0) * 8u;
      v[j] = *reinterpret_cast<const f4a8_t*>(S8 + voff);  // 16B: taps t,t+1 x 4 batches
    }

#pragma unroll
    for (int j = 0; j < 4; ++j) {
      const bool valid = (kfs[j] >= 0.0f) && (kfs[j] < (float)(N_T - 1));
      const float w = valid ? apod_s[dbase + j] : 0.0f;  // wave-uniform addr -> broadcast
      const float al = als[j];
      const __half2* hp = reinterpret_cast<const __half2*>(&v[j]);
      const float2 s0a = __half22float2(hp[0]);  // t:   b0,b1
      const float2 s0b = __half22float2(hp[1]);  // t:   b2,b3
      const float2 s1a = __half22float2(hp[2]);  // t+1: b0,b1
      const float2 s1b = __half22float2(hp[3]);  // t+1: b2,b3
      a0 += w * (s0a.x + al * (s1a.x - s0a.x));
      a1 += w * (s0a.y + al * (s1a.y - s0a.y));
      a2 += w * (s0b.x + al * (s1b.x - s0b.x));
      a3 += w * (s0b.y + al * (s1b.y - s0b.y));
    }
  }

  *reinterpret_cast<float4*>(&red[y][x][0]) = make_float4(a0, a1, a2, a3);
  __syncthreads();

  // Reduce: reinterpret (x,y) as (pixel=x, batch=y). 256 threads = 64 pix x 4 b.
  const float s = red[0][x][y] + red[1][x][y] + red[2][x][y] + red[3][x][y];
  __builtin_nontemporal_store(s * (1.0f / 63.5f),
                              out + (size_t)y * NPIX + blockIdx.x * PIX_PER_BLK + x);
}

// Fallback (no workspace): direct fp32 gather from original layout.
__global__ __launch_bounds__(256) void das_fallback_kernel(
    const float* __restrict__ lut, const float* __restrict__ S,
    float* __restrict__ out) {
  const int lane = threadIdx.x & 63;
  const int p = blockIdx.x * 4 + (threadIdx.x >> 6);

  const float4 lv =
      reinterpret_cast<const float4*>(lut + (size_t)p * 2 * N_DET)[lane];

  float acc0 = 0.f, acc1 = 0.f, acc2 = 0.f, acc3 = 0.f;
  float wsum = 0.f;

#pragma unroll
  for (int j = 0; j < 2; ++j) {
    const int d = 2 * lane + j;
    const float tof = j ? lv.z : lv.x;
    const float a   = j ? lv.w : lv.y;
    const float kf = floorf(tof);
    const bool valid = (kf >= 0.0f) && (kf < (float)(N_T - 1));
    const float kcl = fminf(fmaxf(kf, 0.0f), (float)(N_T - 2));
    const int k0 = (int)kcl;
    const float apd =
        0.5f - 0.5f * cosf(6.28318530717958647692f *
                           (1.0f / (float)(N_DET - 1)) * (float)d);
    wsum += apd;
    const float w = valid ? apd : 0.0f;
    const float om = 1.0f - a;
    const float* row = S + (size_t)d * N_T + k0;
    acc0 += w * (om * row[0 * N_DET * N_T] + a * row[0 * N_DET * N_T + 1]);
    acc1 += w * (om * row[1 * N_DET * N_T] + a * row[1 * N_DET * N_T + 1]);
    acc2 += w * (om * row[2 * N_DET * N_T] + a * row[2 * N_DET * N_T + 1]);
    acc3 += w * (om * row[3 * N_DET * N_T] + a * row[3 * N_DET * N_T + 1]);
  }

#pragma unroll
  for (int off = 32; off > 0; off >>= 1) {
    acc0 += __shfl_xor(acc0, off);
    acc1 += __shfl_xor(acc1, off);
    acc2 += __shfl_xor(acc2, off);
    acc3 += __shfl_xor(acc3, off);
    wsum += __shfl_xor(wsum, off);
  }

  if (lane == 0) {
    const float inv = 1.0f / fmaxf(wsum, 1.17549435e-38f);
    out[0 * NPIX + p] = acc0 * inv;
    out[1 * NPIX + p] = acc1 * inv;
    out[2 * NPIX + p] = acc2 * inv;
    out[3 * NPIX + p] = acc3 * inv;
  }
}

extern "C" void kernel_launch(void* const* d_in, const int* in_sizes, int n_in,
                              void* d_out, int out_size, void* d_ws, size_t ws_size,
                              hipStream_t stream) {
  const float* sino = (const float*)d_in[0];  // (B,1,N_DET,N_T) fp32
  const float* lut  = (const float*)d_in[1];  // (NY,NX,N_DET,2) fp32
  float* out = (float*)d_out;                 // (B,1,NY,NX) fp32

  const size_t need = (size_t)N_DET * N_T * 8;  // 2 MB packed ws
  if (ws_size >= need) {
    float2* ws = (float2*)d_ws;
    sino_pack_kernel<<<(N_DET * N_T) / 256, 256, 0, stream>>>(sino, ws);
    dim3 blk(PIX_PER_BLK, NGRP);
    das_kernel<<<NPIX / PIX_PER_BLK, blk, 0, stream>>>(
        lut, (const unsigned char*)d_ws, out);
  } else {
    das_fallback_kernel<<<NPIX / 4, 256, 0, stream>>>(lut, sino, out);
  }
}

// Round 5
// 121.737 us; speedup vs baseline: 1.1601x; 1.1003x over previous
//
#include <hip/hip_runtime.h>
#include <hip/hip_fp16.h>

#define N_DET 128
#define N_T   2048
#define NPIX  65536   // 256*256
#define NBATCH 4
#define G 8           // detector rows staged in LDS per block (8 x 16 KB = 128 KB)
#define PT 1024       // pixels per block
#define NGB (N_DET / G)

typedef float f4_t __attribute__((ext_vector_type(4)));

// Kernel 1: transpose+pack sino (B, N_DET, N_T) fp32 -> ws (N_DET, N_T) of
// 8-byte records { s_t[b0..b3] } as 4 fp16. ws = 2 MB (L2-resident).
__global__ __launch_bounds__(256) void sino_pack_kernel(
    const float* __restrict__ sino, float2* __restrict__ ws) {
  const int idx = blockIdx.x * blockDim.x + threadIdx.x;  // idx = d*N_T + t
  const __half2 lo = __floats2half2_rn(
      __builtin_nontemporal_load(sino + 0 * N_DET * N_T + idx),
      __builtin_nontemporal_load(sino + 1 * N_DET * N_T + idx));
  const __half2 hi = __floats2half2_rn(
      __builtin_nontemporal_load(sino + 2 * N_DET * N_T + idx),
      __builtin_nontemporal_load(sino + 3 * N_DET * N_T + idx));
  union { struct { __half2 a, b; } h; float2 f; } u;
  u.h.a = lo;
  u.h.b = hi;
  ws[idx] = u.f;
}

// Kernel 2: LDS-gather kernel. Block = (pixel tile of 1024) x (det group of 8).
// The 8 det rows (2048 x 8 B each) live in LDS; sino gathers are ds_read_b64
// (separate LDS pipe - bypasses the TA/vector-memory bottleneck entirely).
// Each thread owns one pixel x 8 dets: its lut read is one full 64 B line.
// Partials accumulate into out via atomicAdd (out pre-zeroed on stream).
__global__ __launch_bounds__(256) void das_lds_kernel(
    const float* __restrict__ lut, const float2* __restrict__ ws,
    float* __restrict__ out) {
  __shared__ float2 sino_s[G * N_T];  // 128 KB

  const int tid = threadIdx.x;
  const int tile = blockIdx.x;  // 0..63
  const int g = blockIdx.y;     // 0..15

  // Prefetch this thread's lut data for all 4 pixel-iters BEFORE staging:
  // 4 iters x 64 B (8 dets x (tof, alpha)). Independent of LDS.
  f4_t l[PT / 256][4];
#pragma unroll
  for (int i = 0; i < PT / 256; ++i) {
    const int p = tile * PT + i * 256 + tid;
    const f4_t* lp =
        reinterpret_cast<const f4_t*>(lut + ((size_t)p * N_DET + g * G) * 2);
#pragma unroll
    for (int j = 0; j < 4; ++j) l[i][j] = lp[j];
  }

  // Stage 8 det rows: 16384 float2 = 8192 float4, coalesced from L2-resident ws.
  {
    const float4* src = reinterpret_cast<const float4*>(ws + (size_t)g * G * N_T);
    float4* dst = reinterpret_cast<float4*>(sino_s);
#pragma unroll
    for (int i = 0; i < 8192 / 256; ++i) dst[tid + i * 256] = src[tid + i * 256];
  }

  // Apodization for this block's 8 dets (wave-uniform, computed in-register).
  float apd[G];
#pragma unroll
  for (int j = 0; j < G; ++j) {
    apd[j] = 0.5f - 0.5f * cosf(6.28318530717958647692f *
                                ((float)(g * G + j) / (float)(N_DET - 1)));
  }
  __syncthreads();

#pragma unroll
  for (int i = 0; i < PT / 256; ++i) {
    const int p = tile * PT + i * 256 + tid;
    float a0 = 0.f, a1 = 0.f, a2 = 0.f, a3 = 0.f;
#pragma unroll
    for (int j = 0; j < G; ++j) {
      const float tof = (j & 1) ? l[i][j >> 1].z : l[i][j >> 1].x;
      const float al  = (j & 1) ? l[i][j >> 1].w : l[i][j >> 1].y;
      const float kf = floorf(tof);
      const bool valid = (kf >= 0.0f) && (kf < (float)(N_T - 1));
      const float kcl = fminf(fmaxf(kf, 0.0f), (float)(N_T - 2));
      const int k0 = (int)kcl;
      const float w = valid ? apd[j] : 0.0f;

      const float2 r0 = sino_s[j * N_T + k0];      // ds_read_b64: tap t
      const float2 r1 = sino_s[j * N_T + k0 + 1];  // ds_read_b64: tap t+1
      const __half2* h0 = reinterpret_cast<const __half2*>(&r0);
      const __half2* h1 = reinterpret_cast<const __half2*>(&r1);
      const float2 s0a = __half22float2(h0[0]);  // t:   b0,b1
      const float2 s0b = __half22float2(h0[1]);  // t:   b2,b3
      const float2 s1a = __half22float2(h1[0]);  // t+1: b0,b1
      const float2 s1b = __half22float2(h1[1]);  // t+1: b2,b3

      a0 += w * (s0a.x + al * (s1a.x - s0a.x));
      a1 += w * (s0a.y + al * (s1a.y - s0a.y));
      a2 += w * (s0b.x + al * (s1b.x - s0b.x));
      a3 += w * (s0b.y + al * (s1b.y - s0b.y));
    }
    const float nrm = 1.0f / 63.5f;  // sum(apod) == 63.5 analytically
    atomicAdd(out + 0 * NPIX + p, a0 * nrm);
    atomicAdd(out + 1 * NPIX + p, a1 * nrm);
    atomicAdd(out + 2 * NPIX + p, a2 * nrm);
    atomicAdd(out + 3 * NPIX + p, a3 * nrm);
  }
}

// Fallback (no workspace): direct fp32 gather from original layout.
__global__ __launch_bounds__(256) void das_fallback_kernel(
    const float* __restrict__ lut, const float* __restrict__ S,
    float* __restrict__ out) {
  const int lane = threadIdx.x & 63;
  const int p = blockIdx.x * 4 + (threadIdx.x >> 6);

  const float4 lv =
      reinterpret_cast<const float4*>(lut + (size_t)p * 2 * N_DET)[lane];

  float acc0 = 0.f, acc1 = 0.f, acc2 = 0.f, acc3 = 0.f;
  float wsum = 0.f;

#pragma unroll
  for (int j = 0; j < 2; ++j) {
    const int d = 2 * lane + j;
    const float tof = j ? lv.z : lv.x;
    const float a   = j ? lv.w : lv.y;
    const float kf = floorf(tof);
    const bool valid = (kf >= 0.0f) && (kf < (float)(N_T - 1));
    const float kcl = fminf(fmaxf(kf, 0.0f), (float)(N_T - 2));
    const int k0 = (int)kcl;
    const float apd =
        0.5f - 0.5f * cosf(6.28318530717958647692f *
                           (1.0f / (float)(N_DET - 1)) * (float)d);
    wsum += apd;
    const float w = valid ? apd : 0.0f;
    const float om = 1.0f - a;
    const float* row = S + (size_t)d * N_T + k0;
    acc0 += w * (om * row[0 * N_DET * N_T] + a * row[0 * N_DET * N_T + 1]);
    acc1 += w * (om * row[1 * N_DET * N_T] + a * row[1 * N_DET * N_T + 1]);
    acc2 += w * (om * row[2 * N_DET * N_T] + a * row[2 * N_DET * N_T + 1]);
    acc3 += w * (om * row[3 * N_DET * N_T] + a * row[3 * N_DET * N_T + 1]);
  }

#pragma unroll
  for (int off = 32; off > 0; off >>= 1) {
    acc0 += __shfl_xor(acc0, off);
    acc1 += __shfl_xor(acc1, off);
    acc2 += __shfl_xor(acc2, off);
    acc3 += __shfl_xor(acc3, off);
    wsum += __shfl_xor(wsum, off);
  }

  if (lane == 0) {
    const float inv = 1.0f / fmaxf(wsum, 1.17549435e-38f);
    out[0 * NPIX + p] = acc0 * inv;
    out[1 * NPIX + p] = acc1 * inv;
    out[2 * NPIX + p] = acc2 * inv;
    out[3 * NPIX + p] = acc3 * inv;
  }
}

extern "C" void kernel_launch(void* const* d_in, const int* in_sizes, int n_in,
                              void* d_out, int out_size, void* d_ws, size_t ws_size,
                              hipStream_t stream) {
  const float* sino = (const float*)d_in[0];  // (B,1,N_DET,N_T) fp32
  const float* lut  = (const float*)d_in[1];  // (NY,NX,N_DET,2) fp32
  float* out = (float*)d_out;                 // (B,1,NY,NX) fp32

  const size_t need = (size_t)N_DET * N_T * 8;  // 2 MB packed ws
  if (ws_size >= need) {
    hipMemsetAsync(d_out, 0, (size_t)out_size * sizeof(float), stream);
    float2* ws = (float2*)d_ws;
    sino_pack_kernel<<<(N_DET * N_T) / 256, 256, 0, stream>>>(sino, ws);
    dim3 grid(NPIX / PT, NGB);
    das_lds_kernel<<<grid, 256, 0, stream>>>(lut, ws, out);
  } else {
    das_fallback_kernel<<<NPIX / 4, 256, 0, stream>>>(lut, sino, out);
  }
}